// Round 5
// baseline (2760.270 us; speedup 1.0000x reference)
//
#include <hip/hip_runtime.h>
#include <float.h>
#include <math.h>

#define DIM 512
#define EPSN 1e-12f

typedef _Float16 f16x8 __attribute__((ext_vector_type(8)));
typedef float f32x4 __attribute__((ext_vector_type(4)));

// ---------------- wave (64-lane) sum ----------------
__device__ inline float wave_sum(float v) {
#pragma unroll
  for (int o = 32; o > 0; o >>= 1) v += __shfl_xor(v, o, 64);
  return v;
}

// one wave per emb row: eepair[j] = { sum(embn^2), 1/max(||emb_j||,eps) }
__global__ __launch_bounds__(256) void emb_norm_kernel(
    const float* __restrict__ emb, float2* __restrict__ eepair) {
  int row = blockIdx.x * 4 + (threadIdx.x >> 6);
  int lane = threadIdx.x & 63;
  const float* p = emb + (size_t)row * DIM;
  float x[8];
  float ss = 0.f;
#pragma unroll
  for (int i = 0; i < 8; ++i) { x[i] = p[i * 64 + lane]; ss += x[i] * x[i]; }
  ss = wave_sum(ss);
  float d = fmaxf(sqrtf(ss), EPSN);
  float ee = 0.f;
#pragma unroll
  for (int i = 0; i < 8; ++i) { float y = x[i] / d; ee += y * y; }
  ee = wave_sum(ee);
  if (lane == 0) eepair[row] = make_float2(ee, 1.0f / d);
}

// one wave per z row: zinv[n] = 1/max(||z_n||,eps)
__global__ __launch_bounds__(256) void z_norm_kernel(
    const float* __restrict__ z, float* __restrict__ zinv) {
  int row = blockIdx.x * 4 + (threadIdx.x >> 6);
  int lane = threadIdx.x & 63;
  const float* p = z + (size_t)row * DIM;
  float ss = 0.f;
#pragma unroll
  for (int i = 0; i < 8; ++i) { float v = p[i * 64 + lane]; ss += v * v; }
  ss = wave_sum(ss);
  if (lane == 0) zinv[row] = 1.0f / fmaxf(sqrtf(ss), EPSN);
}

// ---------------- emb -> hi/lo fp16 in B-fragment order ----------------
// chunk c = (subtile16 * 16 + kc) * 2 + half; each chunk = 64 lanes x 8 f16
// (1 KB). Element (lane = quad*16+col, j) = emb[subtile16*16+col]
// [kc*32 + quad*8 + j], split hi/lo. A wave reading chunk base + lane*16
// gets exactly its MFMA B fragment -- no LDS staging needed at all.
__global__ __launch_bounds__(256) void emb_split_kernel(
    const float* __restrict__ emb, _Float16* __restrict__ swz) {
  int g = blockIdx.x * 256 + threadIdx.x;  // = t*1024 + kc*64 + lane
  int lane = g & 63;
  int kc = (g >> 6) & 15;
  int t = g >> 10;
  int code = t * 16 + (lane & 15);
  int k0 = kc * 32 + (lane >> 4) * 8;
  const float* src = emb + (size_t)code * DIM + k0;
  float4 a = *(const float4*)src;
  float4 b = *(const float4*)(src + 4);
  float v[8] = {a.x, a.y, a.z, a.w, b.x, b.y, b.z, b.w};
  f16x8 h, l;
#pragma unroll
  for (int k = 0; k < 8; ++k) {
    _Float16 hh = (_Float16)v[k];
    h[k] = hh;
    l[k] = (_Float16)(v[k] - (float)hh);
  }
  size_t cbase = ((size_t)(t * 16 + kc) * 2) * 512;  // f16 units
  *(f16x8*)&swz[cbase + lane * 8] = h;
  *(f16x8*)&swz[cbase + 512 + lane * 8] = l;
}

// ---------------- MFMA distance + argmin (LDS-free, barrier-free) --------
// 256 blocks x 256 threads (4 waves). Each wave owns 32 rows as two 16-row
// MFMA blocks with persistent hi/lo fp16 A fragments (AGPR-resident); B
// fragments are loaded straight from the pre-swizzled array into VGPRs
// (global_load_dwordx4, base + lane*16). All 4 waves read the same subtile
// -> L1 serves the redundancy; no __syncthreads in the hot loop, so waves
// drift and one wave's epilogue overlaps another's MFMA issue (the barrier
// drain was the R4 stall). 6 MFMAs per (bh,bl) pair: hh, lh, hl.
#define MFMA16(A, B, C) __builtin_amdgcn_mfma_f32_16x16x32_f16(A, B, C, 0, 0, 0)

__global__ __launch_bounds__(256, 1) void dist_argmin_kernel(
    const float* __restrict__ z, const _Float16* __restrict__ swz,
    const float2* __restrict__ eepair, const float* __restrict__ zinv,
    int ne, int* __restrict__ idxw, float* __restrict__ counts,
    float* __restrict__ out_idx) {
  const int tid = threadIdx.x;
  const int wave = tid >> 6;
  const int lane = tid & 63;
  const int col = lane & 15;
  const int quad = lane >> 4;
  const int r0 = blockIdx.x * 128 + wave * 32;

  // persistent A fragments (hi/lo) for two 16-row blocks
  f16x8 Ah[2][16], Al[2][16];
#pragma unroll
  for (int rb = 0; rb < 2; ++rb) {
    const float* zp = z + (size_t)(r0 + rb * 16 + col) * DIM + quad * 8;
#pragma unroll
    for (int kc = 0; kc < 16; ++kc) {
      float4 a = *(const float4*)(zp + kc * 32);
      float4 b = *(const float4*)(zp + kc * 32 + 4);
      float v[8] = {a.x, a.y, a.z, a.w, b.x, b.y, b.z, b.w};
#pragma unroll
      for (int k = 0; k < 8; ++k) {
        _Float16 h = (_Float16)v[k];
        Ah[rb][kc][k] = h;
        Al[rb][kc][k] = (_Float16)(v[k] - (float)h);
      }
    }
  }

  float zr[2][4];
#pragma unroll
  for (int rb = 0; rb < 2; ++rb)
#pragma unroll
    for (int i = 0; i < 4; ++i)
      zr[rb][i] = zinv[r0 + rb * 16 + quad * 4 + i];

  float best[2][4] = {{FLT_MAX, FLT_MAX, FLT_MAX, FLT_MAX},
                      {FLT_MAX, FLT_MAX, FLT_MAX, FLT_MAX}};
  int bidx[2][4] = {{0, 0, 0, 0}, {0, 0, 0, 0}};

  const _Float16* bp = swz + lane * 8;  // per-lane fragment base
  const int nsub = ne / 16;             // 16-code subtiles

  for (int s = 0; s < nsub; ++s) {
    // load this subtile's 32 B fragments into registers (128 VGPR);
    // compiler interleaves fine-grained vmcnt waits with the MFMAs below
    f16x8 bh[16], bl[16];
#pragma unroll
    for (int kc = 0; kc < 16; ++kc) {
      const _Float16* c0 = bp + ((size_t)(s * 16 + kc) * 2) * 512;
      bh[kc] = *(const f16x8*)c0;
      bl[kc] = *(const f16x8*)(c0 + 512);
    }

    f32x4 acc[2][3];
#pragma unroll
    for (int rb = 0; rb < 2; ++rb)
#pragma unroll
      for (int a = 0; a < 3; ++a) acc[rb][a] = (f32x4){0.f, 0.f, 0.f, 0.f};

#pragma unroll
    for (int kc = 0; kc < 16; ++kc) {
      acc[0][0] = MFMA16(Ah[0][kc], bh[kc], acc[0][0]);
      acc[1][0] = MFMA16(Ah[1][kc], bh[kc], acc[1][0]);
      acc[0][1] = MFMA16(Al[0][kc], bh[kc], acc[0][1]);
      acc[1][1] = MFMA16(Al[1][kc], bh[kc], acc[1][1]);
      acc[0][2] = MFMA16(Ah[0][kc], bl[kc], acc[0][2]);
      acc[1][2] = MFMA16(Ah[1][kc], bl[kc], acc[1][2]);
    }

    // epilogue: score = ee_j - 2*einv_j*zinv_r*dot
    float2 ep = eepair[s * 16 + col];
    float w2 = 2.0f * ep.y;
    int j = s * 16 + col;
#pragma unroll
    for (int rb = 0; rb < 2; ++rb)
#pragma unroll
      for (int i = 0; i < 4; ++i) {
        float d = acc[rb][0][i] + acc[rb][1][i] + acc[rb][2][i];
        float sc = ep.x - w2 * zr[rb][i] * d;
        if (sc < best[rb][i]) { best[rb][i] = sc; bidx[rb][i] = j; }
      }
  }

  // merge across the 16 columns within each quad (xor 1,2,4,8 stays in quad)
#pragma unroll
  for (int rb = 0; rb < 2; ++rb)
#pragma unroll
    for (int i = 0; i < 4; ++i) {
      float bs = best[rb][i];
      int bj = bidx[rb][i];
#pragma unroll
      for (int off = 1; off < 16; off <<= 1) {
        float os = __shfl_xor(bs, off, 64);
        int oi = __shfl_xor(bj, off, 64);
        if (os < bs || (os == bs && oi < bj)) { bs = os; bj = oi; }
      }
      if (col == 0) {
        int row = r0 + rb * 16 + quad * 4 + i;
        idxw[row] = bj;
        out_idx[row] = (float)bj;
        atomicAdd(&counts[bj], 1.0f);
      }
    }
}

// one wave per row: z_q_st = normalize(q); per-block loss partial
__global__ __launch_bounds__(256) void finalize_rows_kernel(
    const float* __restrict__ z, const float* __restrict__ emb,
    const int* __restrict__ idxw, const float* __restrict__ zinv,
    float* __restrict__ out_zq, float* __restrict__ lpart) {
  __shared__ float red[4];
  int row = blockIdx.x * 4 + (threadIdx.x >> 6);
  int lane = threadIdx.x & 63;
  int j = idxw[row];
  const float* zp = z + (size_t)row * DIM;
  const float* qp = emb + (size_t)j * DIM;
  float zl[8], ql[8], tl[8];
  float st = 0.f, sq = 0.f;
#pragma unroll
  for (int i = 0; i < 8; ++i) {
    int k = i * 64 + lane;
    float zv = zp[k], qv = qp[k];
    float t = zv + (qv - zv);  // straight-through, literal arithmetic
    zl[i] = zv; ql[i] = qv; tl[i] = t;
    st += t * t;
    sq += qv * qv;
  }
  st = wave_sum(st);
  sq = wave_sum(sq);
  float dt = fmaxf(sqrtf(st), EPSN);
  float dq = fmaxf(sqrtf(sq), EPSN);
  float zi = zinv[row];
  float lp = 0.f;
#pragma unroll
  for (int i = 0; i < 8; ++i) {
    int k = i * 64 + lane;
    out_zq[(size_t)row * DIM + k] = tl[i] / dt;
    float e = ql[i] / dq - zl[i] * zi;
    lp += e * e;
  }
  lp = wave_sum(lp);
  if (lane == 0) red[threadIdx.x >> 6] = lp;
  __syncthreads();
  if (threadIdx.x == 0) lpart[blockIdx.x] = red[0] + red[1] + red[2] + red[3];
}

// single block: loss scalar (sum of block partials) + perplexity from counts
__global__ __launch_bounds__(256) void scalars_kernel(
    const float* __restrict__ counts, const float* __restrict__ lpart,
    int ne, int nblk, float inv_n, float inv_total,
    float* __restrict__ out_loss, float* __restrict__ out_perp) {
  __shared__ float red[8];
  int tid = threadIdx.x;
  float s = 0.f;
  for (int jj = tid; jj < ne; jj += 256) {
    float p = counts[jj] * inv_n;
    s += p * logf(p + 1e-10f);
  }
  float l = 0.f;
  for (int jj = tid; jj < nblk; jj += 256) l += lpart[jj];
  s = wave_sum(s);
  l = wave_sum(l);
  if ((tid & 63) == 0) { red[tid >> 6] = s; red[4 + (tid >> 6)] = l; }
  __syncthreads();
  if (tid == 0) {
    float t = red[0] + red[1] + red[2] + red[3];
    float lt = red[4] + red[5] + red[6] + red[7];
    *out_perp = expf(-t);
    *out_loss = 1.25f * lt * inv_total;  // (1+BETA)*mean, sg() identity fwd
  }
}

extern "C" void kernel_launch(void* const* d_in, const int* in_sizes, int n_in,
                              void* d_out, int out_size, void* d_ws, size_t ws_size,
                              hipStream_t stream) {
  const float* z = (const float*)d_in[0];
  const float* emb = (const float*)d_in[1];
  float* out = (float*)d_out;
  float* ws = (float*)d_ws;

  const int nrows = in_sizes[0] / DIM;  // 32768
  const int ne = in_sizes[1] / DIM;     // 8192
  const int nfin = nrows / 4;           // finalize blocks

  // workspace layout (floats)
  float2* eepair = (float2*)ws;                  // ne float2
  float* zinv = ws + 2 * ne;                     // nrows
  int* idxw = (int*)(ws + 2 * ne + nrows);       // nrows
  float* counts = ws + 2 * ne + 2 * nrows;       // ne
  float* lpart = counts + ne;                    // nfin
  _Float16* swz = (_Float16*)(lpart + nfin);     // ne*1024 f16 (~16.8 MB)

  float* out_zq = out + 1;
  float* out_idx = out + 1 + (size_t)nrows * DIM;
  float* out_perp = out + (size_t)out_size - 1;

  hipMemsetAsync(counts, 0, ne * sizeof(float), stream);
  emb_norm_kernel<<<ne / 4, 256, 0, stream>>>(emb, eepair);
  z_norm_kernel<<<nrows / 4, 256, 0, stream>>>(z, zinv);
  emb_split_kernel<<<ne * 64 / 256, 256, 0, stream>>>(emb, swz);
  dist_argmin_kernel<<<nrows / 128, 256, 0, stream>>>(z, swz, eepair, zinv, ne,
                                                      idxw, counts, out_idx);
  finalize_rows_kernel<<<nfin, 256, 0, stream>>>(z, emb, idxw, zinv,
                                                 out_zq, lpart);
  scalars_kernel<<<1, 256, 0, stream>>>(counts, lpart, ne, nfin,
                                        1.0f / (float)nrows,
                                        1.0f / (float)((size_t)nrows * DIM),
                                        out, out_perp);
}